// Round 4
// baseline (19374.875 us; speedup 1.0000x reference)
//
#include <hip/hip_runtime.h>

constexpr int SEQ  = 4096;   // timesteps
constexpr int IN   = 512;    // input size
constexpr int RS   = 2048;   // reservoir size
constexpr int GB   = 64;     // blocks in scan kernel
constexpr int BT   = 1024;   // threads per block in scan kernel
constexpr int RING = 8;      // ring depth (epochs); skew bound <= 1
constexpr float INV_SQRT = 0.022097086912079612f; // 1/sqrt(2048)

// ---------------------------------------------------------------------------
// Phase 1: pre = X @ W_in^T, written to out rows 1..SEQ (in-place scan buffer)
// ---------------------------------------------------------------------------
__global__ __launch_bounds__(256)
void gemm_pre_kernel(const float* __restrict__ A, const float* __restrict__ B,
                     float* __restrict__ out) {
    __shared__ float As[64][17];
    __shared__ float Bs[64][17];
    const int tid = threadIdx.x;
    const int tx = tid & 15, ty = tid >> 4;
    const int m0 = blockIdx.x * 64, n0 = blockIdx.y * 64;
    const int lr = tid >> 2;
    const int lk = (tid & 3) * 4;
    float acc[4][4] = {};
    for (int k0 = 0; k0 < IN; k0 += 16) {
        const float4 av = *(const float4*)&A[(size_t)(m0 + lr) * IN + k0 + lk];
        const float4 bv = *(const float4*)&B[(size_t)(n0 + lr) * IN + k0 + lk];
        __syncthreads();
        As[lr][lk + 0] = av.x; As[lr][lk + 1] = av.y;
        As[lr][lk + 2] = av.z; As[lr][lk + 3] = av.w;
        Bs[lr][lk + 0] = bv.x; Bs[lr][lk + 1] = bv.y;
        Bs[lr][lk + 2] = bv.z; Bs[lr][lk + 3] = bv.w;
        __syncthreads();
#pragma unroll
        for (int k = 0; k < 16; ++k) {
            float a[4], b[4];
#pragma unroll
            for (int i = 0; i < 4; ++i) a[i] = As[ty * 4 + i][k];
#pragma unroll
            for (int j = 0; j < 4; ++j) b[j] = Bs[tx * 4 + j][k];
#pragma unroll
            for (int i = 0; i < 4; ++i)
#pragma unroll
                for (int j = 0; j < 4; ++j) acc[i][j] += a[i] * b[j];
        }
    }
#pragma unroll
    for (int i = 0; i < 4; ++i) {
        float4 v = make_float4(acc[i][0], acc[i][1], acc[i][2], acc[i][3]);
        *(float4*)&out[(size_t)(m0 + ty * 4 + i + 1) * RS + n0 + tx * 4] = v;
    }
}

// fast tanh: 1 - 2/(exp(2x)+1); exact saturation at +/-inf, ~1e-7 rel err.
__device__ __forceinline__ float fast_tanh(float x) {
    float e = __expf(2.0f * x);
    return 1.0f - 2.0f * __builtin_amdgcn_rcpf(e + 1.0f);
}

typedef unsigned long long u64;
#define AT_LOAD_U64(p)     __hip_atomic_load((p), __ATOMIC_RELAXED, __HIP_MEMORY_SCOPE_AGENT)
#define AT_STORE_U64(p, v) __hip_atomic_store((p), (v), __ATOMIC_RELAXED, __HIP_MEMORY_SCOPE_AGENT)

// encode a float pair for the ring: set bit 0 of each word (never-zero marker,
// 1-ulp perturbation on decode, ~1e-7 relative -- negligible vs threshold).
__device__ __forceinline__ u64 enc2(float a, float b) {
    return (u64)(__float_as_uint(a) | 1u) |
           ((u64)(__float_as_uint(b) | 1u) << 32);
}

// ---------------------------------------------------------------------------
// Phase 2: persistent scan, barrier-free dataflow, per-wave self-publish.
// ring: RING rows x RS dwords (viewed as RS/2 u64 slots) in d_ws, zeroed at
// call start. Slot word == 0 -> not ready. Block b, wave w owns rows
// r0 = b*32 + 2w, r0+1 -> one u64 slot per wave.
// Per step t: [lane0: zero own slot of row (t+2)%8, load pre as float2]
// overlapped with [all: poll own u64 of row t%8 -> LDS buf t&1] -> barrier ->
// dot(W regs x LDS) -> xor-reduce -> lane0: tanh pair, out store, vmcnt
// drain (orders zero < publish), publish own u64 of row (t+1)%8.
// Skew <= 1 step (publish of t requires full row t-1), so slot reuse at
// distance 8 and pre-zero at distance 2 stay race-free; double-buffered LDS
// keeps one barrier per step safe against fast-wave overwrite.
// ---------------------------------------------------------------------------
__global__ __launch_bounds__(BT, 4)
void reservoir_scan_kernel(const float* __restrict__ W_res,
                           const float* __restrict__ init,
                           float* __restrict__ out,
                           u64* __restrict__ ring) {
    __shared__ float s_state[2][RS];
    const int bid  = blockIdx.x;
    const int tid  = threadIdx.x;
    const int wave = tid >> 6;
    const int lane = tid & 63;
    const int r0   = bid * 32 + wave * 2;
    const int slot = r0 >> 1;            // u64 slot index within a ring row

    // --- W rows r0, r0+1 into registers; pin against rematerialization ---
    const float* wp0 = W_res + (size_t)r0 * RS + lane * 4;
    const float* wp1 = wp0 + RS;
    float4 w0[8], w1[8];
#pragma unroll
    for (int j = 0; j < 8; ++j) {
        w0[j] = *(const float4*)(wp0 + j * 256);
        w1[j] = *(const float4*)(wp1 + j * 256);
    }
#pragma unroll
    for (int j = 0; j < 8; ++j) {
        asm volatile("" : "+v"(w0[j].x), "+v"(w0[j].y), "+v"(w0[j].z), "+v"(w0[j].w));
        asm volatile("" : "+v"(w1[j].x), "+v"(w1[j].y), "+v"(w1[j].z), "+v"(w1[j].w));
    }

    // --- epoch 0: out row 0 = init; publish encoded init into ring row 0 ---
    if (lane == 0) {
        float2 v = *(const float2*)(init + r0);
        *(float2*)(out + r0) = v;
        asm volatile("s_waitcnt vmcnt(0)" ::: "memory");
        AT_STORE_U64(ring + slot, enc2(v.x, v.y));
    }

    for (int t = 0; t < SEQ; ++t) {
        const size_t crow = (size_t)(t & (RING - 1)) * (RS / 2);
        const size_t prow = (size_t)((t + 1) & (RING - 1)) * (RS / 2);
        const size_t zrow = (size_t)((t + 2) & (RING - 1)) * (RS / 2);

        // --- lane0: zero own t+2 slot and preload pre (overlap the poll) ---
        float2 pf;
        if (lane == 0) {
            AT_STORE_U64(ring + zrow + slot, 0ull);
            pf = *(const float2*)(out + (size_t)(t + 1) * RS + r0);
        }

        // --- poll own u64 of ring row t; stage into LDS buffer t&1 ---
        float* sb = s_state[t & 1];
        {
            const u64* pp = ring + crow + tid;
            u64 v = AT_LOAD_U64(pp);
            while (((unsigned)v == 0u) || ((unsigned)(v >> 32) == 0u))
                v = AT_LOAD_U64(pp);
            sb[2 * tid]     = __uint_as_float((unsigned)v);
            sb[2 * tid + 1] = __uint_as_float((unsigned)(v >> 32));
        }
        __syncthreads();

        // --- dot products: W regs x LDS state ---
        float a0 = 0.f, a1 = 0.f;
#pragma unroll
        for (int j = 0; j < 8; ++j) {
            const float4 sv = *(const float4*)&sb[lane * 4 + j * 256];
            a0 += w0[j].x * sv.x + w0[j].y * sv.y + w0[j].z * sv.z + w0[j].w * sv.w;
            a1 += w1[j].x * sv.x + w1[j].y * sv.y + w1[j].z * sv.z + w1[j].w * sv.w;
        }
#pragma unroll
        for (int off = 32; off > 0; off >>= 1) {
            a0 += __shfl_xor(a0, off);
            a1 += __shfl_xor(a1, off);
        }

        // --- lane0: finish both rows, store out, drain, self-publish ---
        if (lane == 0) {
            float s0 = fast_tanh(pf.x + a0) * INV_SQRT;
            float s1 = fast_tanh(pf.y + a1) * INV_SQRT;
            *(float2*)(out + (size_t)(t + 1) * RS + r0) = make_float2(s0, s1);
            asm volatile("s_waitcnt vmcnt(0)" ::: "memory"); // zero < publish
            AT_STORE_U64(ring + prow + slot, enc2(s0, s1));
        }
    }
}

extern "C" void kernel_launch(void* const* d_in, const int* in_sizes, int n_in,
                              void* d_out, int out_size, void* d_ws, size_t ws_size,
                              hipStream_t stream) {
    const float* x     = (const float*)d_in[0];  // (4096, 512)
    const float* init  = (const float*)d_in[1];  // (2048,)
    const float* W_in  = (const float*)d_in[2];  // (2048, 512)
    const float* W_res = (const float*)d_in[3];  // (2048, 2048)
    float* out = (float*)d_out;                  // (4097, 2048)
    u64* ring = (u64*)d_ws;

    hipMemsetAsync(d_ws, 0, (size_t)RING * RS * sizeof(float), stream);
    gemm_pre_kernel<<<dim3(SEQ / 64, RS / 64), 256, 0, stream>>>(x, W_in, out);

    void* args[] = { (void*)&W_res, (void*)&init, (void*)&out, (void*)&ring };
    hipLaunchCooperativeKernel((void*)reservoir_scan_kernel,
                               dim3(GB), dim3(BT), args, 0, stream);
}

// Round 5
// 8434.851 us; speedup vs baseline: 2.2970x; 2.2970x over previous
//
#include <hip/hip_runtime.h>

constexpr int SEQ  = 4096;   // timesteps
constexpr int IN   = 512;    // input size
constexpr int RS   = 2048;   // reservoir size
constexpr int GB   = 64;     // blocks in scan kernel
constexpr int BT   = 1024;   // threads per block in scan kernel
constexpr int RING = 8;      // ring depth (epochs); skew bound <= 1
constexpr float INV_SQRT = 0.022097086912079612f; // 1/sqrt(2048)

// ---------------------------------------------------------------------------
// Phase 1: pre = X @ W_in^T, written to out rows 1..SEQ (in-place scan buffer)
// ---------------------------------------------------------------------------
__global__ __launch_bounds__(256)
void gemm_pre_kernel(const float* __restrict__ A, const float* __restrict__ B,
                     float* __restrict__ out) {
    __shared__ float As[64][17];
    __shared__ float Bs[64][17];
    const int tid = threadIdx.x;
    const int tx = tid & 15, ty = tid >> 4;
    const int m0 = blockIdx.x * 64, n0 = blockIdx.y * 64;
    const int lr = tid >> 2;
    const int lk = (tid & 3) * 4;
    float acc[4][4] = {};
    for (int k0 = 0; k0 < IN; k0 += 16) {
        const float4 av = *(const float4*)&A[(size_t)(m0 + lr) * IN + k0 + lk];
        const float4 bv = *(const float4*)&B[(size_t)(n0 + lr) * IN + k0 + lk];
        __syncthreads();
        As[lr][lk + 0] = av.x; As[lr][lk + 1] = av.y;
        As[lr][lk + 2] = av.z; As[lr][lk + 3] = av.w;
        Bs[lr][lk + 0] = bv.x; Bs[lr][lk + 1] = bv.y;
        Bs[lr][lk + 2] = bv.z; Bs[lr][lk + 3] = bv.w;
        __syncthreads();
#pragma unroll
        for (int k = 0; k < 16; ++k) {
            float a[4], b[4];
#pragma unroll
            for (int i = 0; i < 4; ++i) a[i] = As[ty * 4 + i][k];
#pragma unroll
            for (int j = 0; j < 4; ++j) b[j] = Bs[tx * 4 + j][k];
#pragma unroll
            for (int i = 0; i < 4; ++i)
#pragma unroll
                for (int j = 0; j < 4; ++j) acc[i][j] += a[i] * b[j];
        }
    }
#pragma unroll
    for (int i = 0; i < 4; ++i) {
        float4 v = make_float4(acc[i][0], acc[i][1], acc[i][2], acc[i][3]);
        *(float4*)&out[(size_t)(m0 + ty * 4 + i + 1) * RS + n0 + tx * 4] = v;
    }
}

// fast tanh: 1 - 2/(exp(2x)+1); exact saturation at +/-inf, ~1e-7 rel err.
__device__ __forceinline__ float fast_tanh(float x) {
    float e = __expf(2.0f * x);
    return 1.0f - 2.0f * __builtin_amdgcn_rcpf(e + 1.0f);
}

typedef unsigned long long u64;
#define AT_LOAD_U64(p)     __hip_atomic_load((p), __ATOMIC_RELAXED, __HIP_MEMORY_SCOPE_AGENT)
#define AT_STORE_U64(p, v) __hip_atomic_store((p), (v), __ATOMIC_RELAXED, __HIP_MEMORY_SCOPE_AGENT)
#define AT_STORE_U32(p, v) __hip_atomic_store((p), (v), __ATOMIC_RELAXED, __HIP_MEMORY_SCOPE_AGENT)

// never-zero marker: set bit 0 (1-ulp perturbation on decode, negligible).
__device__ __forceinline__ unsigned enc1(float x) { return __float_as_uint(x) | 1u; }

// ---------------------------------------------------------------------------
// Phase 2: persistent scan, barrier-free dataflow (R2 skeleton).
// ring: RING rows x RS dwords in d_ws, zeroed at call start; word==0 -> not
// ready. Block b owns rows [b*32, b*32+32) (wave w: rows b*32+2w, +2w+1).
// Per step t:
//   stage: thread tid polls u64 slot tid of ring row t%8 (s_sleep backoff);
//          the 16 threads whose slot lies in the block's OWN 128B slice read
//          s_pub (decoded, LDS) instead -- no self L3 round trip.
//   sync1; wave0 zeroes own 128B of row (t+2)%8 (overlaps dot);
//   dot (W regs x LDS) -> 6-level shfl reduce;
//   lane<2: tanh finish, plain out store, decoded value -> s_pub;
//   sync2; wave0: s_waitcnt vmcnt(0) (orders zero < publish), publish own
//   32 dwords of row (t+1)%8 as one coalesced 128B sc1 store.
// Skew <= 1 step => slot reuse at distance 8 / pre-zero at distance 2 safe.
// ---------------------------------------------------------------------------
__global__ __launch_bounds__(BT, 1)
void reservoir_scan_kernel(const float* __restrict__ W_res,
                           const float* __restrict__ init,
                           float* __restrict__ out,
                           unsigned* __restrict__ ring32) {
    __shared__ float s_state[RS];
    __shared__ float s_pub[32];
    u64* ring = (u64*)ring32;
    const int bid  = blockIdx.x;
    const int tid  = threadIdx.x;
    const int wave = tid >> 6;
    const int lane = tid & 63;
    const int r0   = bid * 32 + wave * 2;

    // --- W rows r0, r0+1 into registers; pin against rematerialization ---
    const float* wp0 = W_res + (size_t)r0 * RS + lane * 4;
    const float* wp1 = wp0 + RS;
    float4 w0[8], w1[8];
#pragma unroll
    for (int j = 0; j < 8; ++j) {
        w0[j] = *(const float4*)(wp0 + j * 256);
        w1[j] = *(const float4*)(wp1 + j * 256);
    }
#pragma unroll
    for (int j = 0; j < 8; ++j) {
        asm volatile("" : "+v"(w0[j].x), "+v"(w0[j].y), "+v"(w0[j].z), "+v"(w0[j].w));
        asm volatile("" : "+v"(w1[j].x), "+v"(w1[j].y), "+v"(w1[j].z), "+v"(w1[j].w));
    }

    // --- epoch 0: out row 0 = init; publish encoded init; seed s_pub ---
    if (wave == 0 && lane < 32) {
        float v = init[bid * 32 + lane];
        out[bid * 32 + lane] = v;
        s_pub[lane] = v;
        AT_STORE_U32(ring32 + bid * 32 + lane, enc1(v));  // row 0 pre-zeroed
    }
    __syncthreads();

    for (int t = 0; t < SEQ; ++t) {
        const size_t crow = (size_t)(t & (RING - 1)) * (RS / 2);        // u64
        const size_t zrow = (size_t)((t + 2) & (RING - 1)) * (RS / 2);  // u64
        const size_t prow = (size_t)((t + 1) & (RING - 1)) * RS;        // u32

        // --- lane<2: preload pre early (overlaps the poll) ---
        float pre = 0.f;
        if (lane < 2) pre = out[(size_t)(t + 1) * RS + r0 + lane];

        // --- stage state row t into LDS ---
        if ((tid >> 4) == bid) {
            // own 128B slice: take decoded values from LDS, skip the L3 RT
            const int k = tid & 15;
            s_state[2 * tid]     = s_pub[2 * k];
            s_state[2 * tid + 1] = s_pub[2 * k + 1];
        } else {
            const u64* pp = ring + crow + tid;
            u64 v = AT_LOAD_U64(pp);
            while (((unsigned)v == 0u) || ((unsigned)(v >> 32) == 0u)) {
                __builtin_amdgcn_s_sleep(1);   // throttle spin traffic
                v = AT_LOAD_U64(pp);
            }
            s_state[2 * tid]     = __uint_as_float((unsigned)v);
            s_state[2 * tid + 1] = __uint_as_float((unsigned)(v >> 32));
        }
        __syncthreads();

        // --- wave0: zero own 128B of ring row t+2 (overlaps the dot) ---
        if (wave == 0 && lane < 16)
            AT_STORE_U64(ring + zrow + bid * 16 + lane, 0ull);

        // --- dot products: W regs x LDS state ---
        float a0 = 0.f, a1 = 0.f;
#pragma unroll
        for (int j = 0; j < 8; ++j) {
            const float4 sv = *(const float4*)&s_state[lane * 4 + j * 256];
            a0 += w0[j].x * sv.x + w0[j].y * sv.y + w0[j].z * sv.z + w0[j].w * sv.w;
            a1 += w1[j].x * sv.x + w1[j].y * sv.y + w1[j].z * sv.z + w1[j].w * sv.w;
        }
#pragma unroll
        for (int off = 32; off > 0; off >>= 1) {
            a0 += __shfl_xor(a0, off);
            a1 += __shfl_xor(a1, off);
        }

        // --- finish rows r0 (lane 0), r0+1 (lane 1); decoded -> s_pub ---
        if (lane < 2) {
            float a = lane ? a1 : a0;
            float s = fast_tanh(pre + a) * INV_SQRT;
            out[(size_t)(t + 1) * RS + r0 + lane] = s;   // plain store
            s_pub[wave * 2 + lane] = s;
        }
        __syncthreads();

        // --- publish: one coalesced 128B sc1 store; drain orders zero<pub ---
        if (wave == 0 && lane < 32) {
            asm volatile("s_waitcnt vmcnt(0)" ::: "memory");
            AT_STORE_U32(ring32 + prow + bid * 32 + lane, enc1(s_pub[lane]));
        }
    }
}

extern "C" void kernel_launch(void* const* d_in, const int* in_sizes, int n_in,
                              void* d_out, int out_size, void* d_ws, size_t ws_size,
                              hipStream_t stream) {
    const float* x     = (const float*)d_in[0];  // (4096, 512)
    const float* init  = (const float*)d_in[1];  // (2048,)
    const float* W_in  = (const float*)d_in[2];  // (2048, 512)
    const float* W_res = (const float*)d_in[3];  // (2048, 2048)
    float* out = (float*)d_out;                  // (4097, 2048)
    unsigned* ring = (unsigned*)d_ws;

    hipMemsetAsync(d_ws, 0, (size_t)RING * RS * sizeof(float), stream);
    gemm_pre_kernel<<<dim3(SEQ / 64, RS / 64), 256, 0, stream>>>(x, W_in, out);

    void* args[] = { (void*)&W_res, (void*)&init, (void*)&out, (void*)&ring };
    hipLaunchCooperativeKernel((void*)reservoir_scan_kernel,
                               dim3(GB), dim3(BT), args, 0, stream);
}

// Round 6
// 8159.486 us; speedup vs baseline: 2.3745x; 1.0337x over previous
//
#include <hip/hip_runtime.h>

constexpr int SEQ  = 4096;   // timesteps
constexpr int IN   = 512;    // input size
constexpr int RS   = 2048;   // reservoir size
constexpr int GB   = 64;     // blocks in scan kernel
constexpr int BT   = 1024;   // threads per block in scan kernel
constexpr int RING = 8;      // ring depth (epochs); skew bound <= 1
constexpr float INV_SQRT = 0.022097086912079612f; // 1/sqrt(2048)

// ---------------------------------------------------------------------------
// Phase 1: pre = X @ W_in^T, written to out rows 1..SEQ (in-place scan buffer)
// ---------------------------------------------------------------------------
__global__ __launch_bounds__(256)
void gemm_pre_kernel(const float* __restrict__ A, const float* __restrict__ B,
                     float* __restrict__ out) {
    __shared__ float As[64][17];
    __shared__ float Bs[64][17];
    const int tid = threadIdx.x;
    const int tx = tid & 15, ty = tid >> 4;
    const int m0 = blockIdx.x * 64, n0 = blockIdx.y * 64;
    const int lr = tid >> 2;
    const int lk = (tid & 3) * 4;
    float acc[4][4] = {};
    for (int k0 = 0; k0 < IN; k0 += 16) {
        const float4 av = *(const float4*)&A[(size_t)(m0 + lr) * IN + k0 + lk];
        const float4 bv = *(const float4*)&B[(size_t)(n0 + lr) * IN + k0 + lk];
        __syncthreads();
        As[lr][lk + 0] = av.x; As[lr][lk + 1] = av.y;
        As[lr][lk + 2] = av.z; As[lr][lk + 3] = av.w;
        Bs[lr][lk + 0] = bv.x; Bs[lr][lk + 1] = bv.y;
        Bs[lr][lk + 2] = bv.z; Bs[lr][lk + 3] = bv.w;
        __syncthreads();
#pragma unroll
        for (int k = 0; k < 16; ++k) {
            float a[4], b[4];
#pragma unroll
            for (int i = 0; i < 4; ++i) a[i] = As[ty * 4 + i][k];
#pragma unroll
            for (int j = 0; j < 4; ++j) b[j] = Bs[tx * 4 + j][k];
#pragma unroll
            for (int i = 0; i < 4; ++i)
#pragma unroll
                for (int j = 0; j < 4; ++j) acc[i][j] += a[i] * b[j];
        }
    }
#pragma unroll
    for (int i = 0; i < 4; ++i) {
        float4 v = make_float4(acc[i][0], acc[i][1], acc[i][2], acc[i][3]);
        *(float4*)&out[(size_t)(m0 + ty * 4 + i + 1) * RS + n0 + tx * 4] = v;
    }
}

// fast tanh: 1 - 2/(exp(2x)+1); exact saturation at +/-inf, ~1e-7 rel err.
__device__ __forceinline__ float fast_tanh(float x) {
    float e = __expf(2.0f * x);
    return 1.0f - 2.0f * __builtin_amdgcn_rcpf(e + 1.0f);
}

typedef unsigned long long u64;
#define AT_LOAD_U64(p)     __hip_atomic_load((p), __ATOMIC_RELAXED, __HIP_MEMORY_SCOPE_AGENT)
#define AT_STORE_U32(p, v) __hip_atomic_store((p), (v), __ATOMIC_RELAXED, __HIP_MEMORY_SCOPE_AGENT)

// ---------------------------------------------------------------------------
// Phase 2: persistent scan, barrier-free dataflow with EPOCH-PARITY tags.
// ring: RING rows x RS dwords in d_ws, memset-0 at call start (tag bit = 0).
// Epoch e (state_e) lives in row e%8; every dword carries tag bit0 =
// ((e>>3)&1)^1 -- wrap 0 publishes tag 1 (distinct from memset 0), wrap 1
// tag 0 (distinct from wrap 0's stale tag 1), etc. Consumer of epoch e polls
// for tag ((e>>3)&1)^1; stale epoch e-8 always carries the opposite tag, and
// skew <= 1 (all-to-all dependency) rules out ABA at distance 16.
// => NO ring zeroing, NO vmcnt drain: publish is a bare coalesced 128B sc1
// store right after sync2. Decode keeps the tag bit (1-ulp perturbation).
// Block b owns rows [b*32, b*32+32) (wave w: rows b*32+2w, +2w+1); its 16
// "own-slice" threads read s_pub from LDS instead of self-polling L3.
// ---------------------------------------------------------------------------
__global__ __launch_bounds__(BT, 1)
void reservoir_scan_kernel(const float* __restrict__ W_res,
                           const float* __restrict__ init,
                           float* __restrict__ out,
                           unsigned* __restrict__ ring32) {
    __shared__ float s_state[RS];
    __shared__ float s_pub[32];
    u64* ring = (u64*)ring32;
    const int bid  = blockIdx.x;
    const int tid  = threadIdx.x;
    const int wave = tid >> 6;
    const int lane = tid & 63;
    const int r0   = bid * 32 + wave * 2;

    // --- W rows r0, r0+1 into registers; pin against rematerialization ---
    const float* wp0 = W_res + (size_t)r0 * RS + lane * 4;
    const float* wp1 = wp0 + RS;
    float4 w0[8], w1[8];
#pragma unroll
    for (int j = 0; j < 8; ++j) {
        w0[j] = *(const float4*)(wp0 + j * 256);
        w1[j] = *(const float4*)(wp1 + j * 256);
    }
#pragma unroll
    for (int j = 0; j < 8; ++j) {
        asm volatile("" : "+v"(w0[j].x), "+v"(w0[j].y), "+v"(w0[j].z), "+v"(w0[j].w));
        asm volatile("" : "+v"(w1[j].x), "+v"(w1[j].y), "+v"(w1[j].z), "+v"(w1[j].w));
    }

    // --- epoch 0 (wrap 0, tag 1): out row 0 = init; publish; seed s_pub ---
    if (wave == 0 && lane < 32) {
        float v = init[bid * 32 + lane];
        out[bid * 32 + lane] = v;
        s_pub[lane] = v;
        AT_STORE_U32(ring32 + bid * 32 + lane, __float_as_uint(v) | 1u);
    }
    __syncthreads();

    for (int t = 0; t < SEQ; ++t) {
        const size_t crow = (size_t)(t & (RING - 1)) * (RS / 2);        // u64
        const size_t prow = (size_t)((t + 1) & (RING - 1)) * RS;        // u32
        const unsigned tag_c = ((unsigned)(t >> 3) & 1u) ^ 1u;          // consume
        const unsigned tag_p = ((unsigned)((t + 1) >> 3) & 1u) ^ 1u;    // publish

        // --- lane<2: preload pre early (overlaps the poll) ---
        float pre = 0.f;
        if (lane < 2) pre = out[(size_t)(t + 1) * RS + r0 + lane];

        // --- stage state row t into LDS ---
        if ((tid >> 4) == bid) {
            // own 128B slice: take decoded values from LDS, skip the L3 RT
            const int k = tid & 15;
            s_state[2 * tid]     = s_pub[2 * k];
            s_state[2 * tid + 1] = s_pub[2 * k + 1];
        } else {
            const u64* pp = ring + crow + tid;
            u64 v = AT_LOAD_U64(pp);
            while (((((unsigned)v ^ tag_c) & 1u) |
                    (((unsigned)(v >> 32) ^ tag_c) & 1u)) != 0u)
                v = AT_LOAD_U64(pp);
            s_state[2 * tid]     = __uint_as_float((unsigned)v);
            s_state[2 * tid + 1] = __uint_as_float((unsigned)(v >> 32));
        }
        __syncthreads();

        // --- dot products: W regs x LDS state ---
        float a0 = 0.f, a1 = 0.f;
#pragma unroll
        for (int j = 0; j < 8; ++j) {
            const float4 sv = *(const float4*)&s_state[lane * 4 + j * 256];
            a0 += w0[j].x * sv.x + w0[j].y * sv.y + w0[j].z * sv.z + w0[j].w * sv.w;
            a1 += w1[j].x * sv.x + w1[j].y * sv.y + w1[j].z * sv.z + w1[j].w * sv.w;
        }
#pragma unroll
        for (int off = 32; off > 0; off >>= 1) {
            a0 += __shfl_xor(a0, off);
            a1 += __shfl_xor(a1, off);
        }

        // --- finish rows r0 (lane 0), r0+1 (lane 1); decoded -> s_pub ---
        if (lane < 2) {
            float a = lane ? a1 : a0;
            float s = fast_tanh(pre + a) * INV_SQRT;
            out[(size_t)(t + 1) * RS + r0 + lane] = s;   // plain store
            s_pub[wave * 2 + lane] = s;
        }
        __syncthreads();

        // --- publish: bare coalesced 128B sc1 store with parity tag ---
        if (wave == 0 && lane < 32) {
            unsigned bits = __float_as_uint(s_pub[lane]);
            AT_STORE_U32(ring32 + prow + bid * 32 + lane,
                         (bits & ~1u) | tag_p);
        }
    }
}

extern "C" void kernel_launch(void* const* d_in, const int* in_sizes, int n_in,
                              void* d_out, int out_size, void* d_ws, size_t ws_size,
                              hipStream_t stream) {
    const float* x     = (const float*)d_in[0];  // (4096, 512)
    const float* init  = (const float*)d_in[1];  // (2048,)
    const float* W_in  = (const float*)d_in[2];  // (2048, 512)
    const float* W_res = (const float*)d_in[3];  // (2048, 2048)
    float* out = (float*)d_out;                  // (4097, 2048)
    unsigned* ring = (unsigned*)d_ws;

    hipMemsetAsync(d_ws, 0, (size_t)RING * RS * sizeof(float), stream);
    gemm_pre_kernel<<<dim3(SEQ / 64, RS / 64), 256, 0, stream>>>(x, W_in, out);

    void* args[] = { (void*)&W_res, (void*)&init, (void*)&out, (void*)&ring };
    hipLaunchCooperativeKernel((void*)reservoir_scan_kernel,
                               dim3(GB), dim3(BT), args, 0, stream);
}